// Round 2
// baseline (257.333 us; speedup 1.0000x reference)
//
#include <hip/hip_runtime.h>

#define EPSF 1e-6f

typedef __bf16 bf16;
typedef bf16 bf16x4 __attribute__((ext_vector_type(4)));
typedef bf16 bf16x8 __attribute__((ext_vector_type(8)));
typedef float f32x4 __attribute__((ext_vector_type(4)));
typedef unsigned int u32;

// N=8, L=S=4096, E=256, H=8, D=32.
// MFMA 16x16x32 bf16 frags: A[m=lane&15][k=(lane>>4)*8+j], B[k][n=lane&15],
// C/D: col=lane&15, row=(lane>>4)*4+reg.
//
// R6: occupancy fix. kvproj s-tile 128->64 (grid 1024, LDS 36.9 KB -> 4
// blocks/CU); attn l-tile 64->32 (grid 1024, LDS ~22.7 KB -> 4 blocks/CU).
// KVf/Ksum atomic accumulators sliced 4-way by s-tile to cut same-address
// contention; attn sums the 4 L2-hot slices on load.

__device__ __forceinline__ void async_ld16(const void* g, void* l) {
    __builtin_amdgcn_global_load_lds(
        (const __attribute__((address_space(1))) u32*)g,
        (__attribute__((address_space(3))) u32*)l, 16, 0, 0);
}

__global__ __launch_bounds__(256) void wconv(
    const float* __restrict__ Wq, const float* __restrict__ Wk,
    const float* __restrict__ Wv, const float* __restrict__ Wm,
    bf16* __restrict__ Wb)
{
    const int b = blockIdx.x, t = threadIdx.x;
    const int m = b >> 6;
    const float* S = (m == 0) ? Wq : (m == 1) ? Wk : (m == 2) ? Wv : Wm;
    const int idx = (b & 63) * 1024 + t * 4;
    float4 v = *(const float4*)(S + idx);
    bf16x4 p = {(bf16)v.x, (bf16)v.y, (bf16)v.z, (bf16)v.w};
    *(bf16x4*)(Wb + (size_t)m * 65536 + idx) = p;
}

// ---------------------------------------------------------------------------
// kvproj (fused): per (coltile, n, s-tile64) block computes K-proj AND V-proj
// tiles (z-loop, staging reused), then partial KV + Ksum via in-LDS MFMA and
// sliced f32 atomicAdd. grid (2, 512), 256 threads.
// Wave layout: each wave = all 64 rows x 32 cols (= one head).
// LDS: Kf [128 col][72 s] @0 (18432); staging Xs(8192)+Ws(8192) @18432;
//      Vm [128][72] @18432 aliases staging. Total 36864 -> 4 blocks/CU.
// ---------------------------------------------------------------------------
__global__ __launch_bounds__(256) void kvproj(
    const float* __restrict__ kin, const float* __restrict__ vin,
    const bf16* __restrict__ Wb,
    const float* __restrict__ bk, const float* __restrict__ bv,
    const int* __restrict__ kv_mask,
    float* __restrict__ KVf, float* __restrict__ Ksum)
{
    const int bx = blockIdx.x;                 // coltile (4 heads each)
    const int j0 = bx * 128;
    const int n  = blockIdx.y >> 6;
    const int st = blockIdx.y & 63;
    const int s0 = st * 64;
    const int slice = st & 3;
    const size_t R0 = (size_t)n * 4096 + s0;

    const int t = threadIdx.x, lane = t & 63, w = t >> 6;
    const int ln15 = lane & 15, lg = lane >> 4;
    const int wn = w * 32;                     // wave's col base (one head)
    const int wbase = t & ~63;

    __shared__ __align__(16) char smem[36864];
    bf16*  Kf_ld = (bf16*)smem;                      // [128 col][72 s]
    float* Xs    = (float*)(smem + 18432);           // 8192 B staging
    bf16*  Ws    = (bf16*)(smem + 18432 + 8192);     // 8192 B staging
    bf16*  Vm_ld = (bf16*)(smem + 18432);            // [128][72], aliases staging

    // kv-mask for this tile's 64 rows (same for K and V phases)
    float mv[4][4];
    #pragma unroll
    for (int mi = 0; mi < 4; ++mi)
        #pragma unroll
        for (int r = 0; r < 4; ++r)
            mv[mi][r] = kv_mask[R0 + mi * 16 + lg * 4 + r] ? 1.f : 0.f;

    #pragma unroll
    for (int z = 0; z < 2; ++z) {
        const float* X    = z ? vin : kin;
        const bf16*  W    = Wb + (size_t)(z + 1) * 65536;   // Wk, Wv
        const float* bias = z ? bv : bk;
        bf16* Yt          = z ? Vm_ld : Kf_ld;

        f32x4 acc[4][2] = {};

        for (int k0 = 0; k0 < 256; k0 += 32) {
            #pragma unroll
            for (int i = 0; i < 2; ++i) {     // X: 512 16B-slots (64 rows x 32 f32)
                const int c = i * 256 + t, row = c >> 3, sc = c & 7;
                async_ld16(X + (R0 + row) * 256 + k0 + ((sc ^ (row & 7)) * 4),
                           Xs + (size_t)(i * 256 + wbase) * 4);
            }
            #pragma unroll
            for (int i = 0; i < 2; ++i) {     // W: 512 slots, swizzle over row-pairs
                const int c = i * 256 + t, g = c >> 3, c8 = c & 7;
                const int c8s = c8 ^ (g & 7);
                const int wrow = g * 2 + (c8s >> 2), gch = c8s & 3;
                async_ld16(W + (size_t)(j0 + wrow) * 256 + k0 + gch * 8,
                           Ws + (size_t)(i * 256 + wbase) * 8);
            }
            __syncthreads();

            bf16x8 a[4], b[2];
            #pragma unroll
            for (int mi = 0; mi < 4; ++mi) {
                const int r = mi * 16 + ln15, rb = r & 7;
                f32x4 x0 = *(const f32x4*)&Xs[r * 32 + (((lg * 2)     ^ rb) * 4)];
                f32x4 x1 = *(const f32x4*)&Xs[r * 32 + (((lg * 2 + 1) ^ rb) * 4)];
                a[mi] = bf16x8{(bf16)x0[0], (bf16)x0[1], (bf16)x0[2], (bf16)x0[3],
                               (bf16)x1[0], (bf16)x1[1], (bf16)x1[2], (bf16)x1[3]};
            }
            #pragma unroll
            for (int ni = 0; ni < 2; ++ni) {
                const int wr = wn + ni * 16 + ln15, g = wr >> 1;
                const int c8 = ((wr & 1) * 4 + lg) ^ (g & 7);
                b[ni] = *(const bf16x8*)&Ws[g * 64 + c8 * 8];
            }
            #pragma unroll
            for (int mi = 0; mi < 4; ++mi)
                #pragma unroll
                for (int ni = 0; ni < 2; ++ni)
                    acc[mi][ni] = __builtin_amdgcn_mfma_f32_16x16x32_bf16(
                        a[mi], b[ni], acc[mi][ni], 0, 0, 0);
            __syncthreads();
        }

        // epilogue: bias (+elu+1 for K), mask, transpose to [col][s] in LDS.
        // (No /s on Vm: reference's /s and *s cancel.)
        float bb[2];
        #pragma unroll
        for (int ni = 0; ni < 2; ++ni) bb[ni] = bias[j0 + wn + ni * 16 + ln15];
        #pragma unroll
        for (int ni = 0; ni < 2; ++ni) {
            const int col = wn + ni * 16 + ln15;
            #pragma unroll
            for (int mi = 0; mi < 4; ++mi) {
                const int rowb = mi * 16 + lg * 4;
                bf16x4 pk;
                #pragma unroll
                for (int r = 0; r < 4; ++r) {
                    float x = acc[mi][ni][r] + bb[ni];
                    if (z == 0) x = (x > 0.f) ? (x + 1.f) : __expf(x);
                    pk[r] = (bf16)(x * mv[mi][r]);
                }
                *(bf16x4*)&Yt[col * 72 + rowb] = pk;
            }
        }
        __syncthreads();
    }

    // ---- Ksum partial: col-sums over this tile's 64 s-rows ----
    {
        const int c = t >> 1, sh = t & 1;
        const bf16* kp = Kf_ld + c * 72 + sh * 32;
        float s = 0.f;
        #pragma unroll
        for (int j = 0; j < 4; ++j) {
            bf16x8 vv = *(const bf16x8*)(kp + j * 8);
            #pragma unroll
            for (int jj = 0; jj < 8; ++jj) s += (float)vv[jj];
        }
        s += __shfl_xor(s, 1);
        if (sh == 0) atomicAdd(&Ksum[slice * 2048 + n * 256 + j0 + c], s);
    }

    // ---- partial KV: wave w -> head bx*4+w, 32x32 over k-dim s=64 ----
    {
        const int cb = wn;                     // head-local col base in tile
        f32x4 c2[2][2] = {};
        #pragma unroll
        for (int step = 0; step < 2; ++step) {
            const int sb = step * 32 + lg * 8;
            bf16x8 a[2], b[2];
            #pragma unroll
            for (int mi = 0; mi < 2; ++mi)
                a[mi] = *(const bf16x8*)&Kf_ld[(cb + mi * 16 + ln15) * 72 + sb];
            #pragma unroll
            for (int nj = 0; nj < 2; ++nj)
                b[nj] = *(const bf16x8*)&Vm_ld[(cb + nj * 16 + ln15) * 72 + sb];
            #pragma unroll
            for (int mi = 0; mi < 2; ++mi)
                #pragma unroll
                for (int nj = 0; nj < 2; ++nj)
                    c2[mi][nj] = __builtin_amdgcn_mfma_f32_16x16x32_bf16(
                        a[mi], b[nj], c2[mi][nj], 0, 0, 0);
        }
        // D: col(v)=ln15, row(d)=lg*4+r -> store [v][d] (v-major).
        float* kvh = KVf + (size_t)slice * 65536 + (size_t)((n * 8 + bx * 4 + w) * 1024);
        #pragma unroll
        for (int mi = 0; mi < 2; ++mi)
            #pragma unroll
            for (int nj = 0; nj < 2; ++nj)
                #pragma unroll
                for (int r = 0; r < 4; ++r)
                    atomicAdd(&kvh[(nj * 16 + ln15) * 32 + mi * 16 + lg * 4 + r],
                              c2[mi][nj][r]);
    }
}

// ---------------------------------------------------------------------------
// attn: fused Q-proj (staged core) + linear attention + merge GEMM.
// grid (128, 8), 32-row l-tile, 256 threads, ~22.7 KB LDS -> 4 blocks/CU.
// KV read as f32 (4 L2-hot slices summed) and converted in-register.
// ---------------------------------------------------------------------------
__global__ __launch_bounds__(256) void attn(
    const float* __restrict__ qin, const bf16* __restrict__ Wb,
    const float* __restrict__ bq, const int* __restrict__ q_mask,
    const float* __restrict__ KVf, const float* __restrict__ Ksum,
    float* __restrict__ out)
{
    const int n = blockIdx.y, l0 = blockIdx.x * 32;
    const size_t R0 = (size_t)n * 4096 + l0;
    const int t = threadIdx.x, lane = t & 63, w = t >> 6;
    const int ln15 = lane & 15, lg = lane >> 4;
    const int wn = w * 64;
    const int wbase = t & ~63;

    const bf16* Wq = Wb;
    const bf16* Wm = Wb + 3 * 65536;

    __shared__ __align__(16) char smem[20480];
    float* Xs  = (float*)smem;           //  4096 B: q tile 32x32 f32 swizzled
    bf16*  Wst = (bf16*)(smem + 4096);   // 16384 B: Wq tile 256x32 swizzled
    bf16 (*Qs)[264] = (bf16(*)[264])smem;   // 32x264 bf16, aliases staging
    __shared__ float KSs[256];
    __shared__ float Dens[32][9];

    {   // Ksum: sum 4 slices (L2-hot)
        float s = 0.f;
        #pragma unroll
        for (int sl = 0; sl < 4; ++sl) s += Ksum[sl * 2048 + n * 256 + t];
        KSs[t] = s;
    }

    {   // ---- Q-projection, staged ----
        f32x4 acc[2][4] = {};
        for (int k0 = 0; k0 < 256; k0 += 32) {
            {   // X: 256 slots (32 rows x 32 f32)
                const int row = t >> 3, sc = t & 7;
                async_ld16(qin + (R0 + row) * 256 + k0 + ((sc ^ (row & 7)) * 4),
                           Xs + (size_t)wbase * 4);
            }
            #pragma unroll
            for (int i = 0; i < 4; ++i) {     // W: 1024 slots (all 256 rows)
                const int c = i * 256 + t, g = c >> 3, c8 = c & 7;
                const int c8s = c8 ^ (g & 7);
                const int wrow = g * 2 + (c8s >> 2), gch = c8s & 3;
                async_ld16(Wq + (size_t)wrow * 256 + k0 + gch * 8,
                           Wst + (size_t)(i * 256 + wbase) * 8);
            }
            __syncthreads();

            bf16x8 a[2], b[4];
            #pragma unroll
            for (int mi = 0; mi < 2; ++mi) {
                const int r = mi * 16 + ln15, rb = r & 7;
                f32x4 x0 = *(const f32x4*)&Xs[r * 32 + (((lg * 2)     ^ rb) * 4)];
                f32x4 x1 = *(const f32x4*)&Xs[r * 32 + (((lg * 2 + 1) ^ rb) * 4)];
                a[mi] = bf16x8{(bf16)x0[0], (bf16)x0[1], (bf16)x0[2], (bf16)x0[3],
                               (bf16)x1[0], (bf16)x1[1], (bf16)x1[2], (bf16)x1[3]};
            }
            #pragma unroll
            for (int ni = 0; ni < 4; ++ni) {
                const int wr = wn + ni * 16 + ln15, g = wr >> 1;
                const int c8 = ((wr & 1) * 4 + lg) ^ (g & 7);
                b[ni] = *(const bf16x8*)&Wst[g * 64 + c8 * 8];
            }
            #pragma unroll
            for (int mi = 0; mi < 2; ++mi)
                #pragma unroll
                for (int ni = 0; ni < 4; ++ni)
                    acc[mi][ni] = __builtin_amdgcn_mfma_f32_16x16x32_bf16(
                        a[mi], b[ni], acc[mi][ni], 0, 0, 0);
            __syncthreads();
        }
        float bb[4];
        #pragma unroll
        for (int ni = 0; ni < 4; ++ni) bb[ni] = bq[wn + ni * 16 + ln15];
        float mv[2][4];
        #pragma unroll
        for (int mi = 0; mi < 2; ++mi)
            #pragma unroll
            for (int r = 0; r < 4; ++r)
                mv[mi][r] = q_mask[R0 + mi * 16 + lg * 4 + r] ? 1.f : 0.f;
        #pragma unroll
        for (int mi = 0; mi < 2; ++mi)
            #pragma unroll
            for (int r = 0; r < 4; ++r) {
                const int row = mi * 16 + lg * 4 + r;
                #pragma unroll
                for (int ni = 0; ni < 4; ++ni) {
                    float x = acc[mi][ni][r] + bb[ni];
                    x = (x > 0.f) ? (x + 1.f) : __expf(x);
                    Qs[row][wn + ni * 16 + ln15] = (bf16)(x * mv[mi][r]);
                }
            }
    }
    __syncthreads();

    {   // den[l][h]
        const int l = t & 31, h = t >> 5;
        float s = 0.f;
        #pragma unroll
        for (int d8 = 0; d8 < 4; ++d8) {
            bf16x8 qv = *(const bf16x8*)&Qs[l][h * 32 + d8 * 8];
            #pragma unroll
            for (int jj = 0; jj < 8; ++jj)
                s += (float)qv[jj] * KSs[h * 32 + d8 * 8 + jj];
        }
        Dens[l][h] = s;
    }
    __syncthreads();

    #pragma unroll
    for (int hh = 0; hh < 2; ++hh) {   // num + normalize (wave-disjoint cols)
        const int h = w * 2 + hh;
        const size_t kvbase = (size_t)((n * 8 + h) * 1024);
        bf16x8 a[2], b[2];
        #pragma unroll
        for (int mi = 0; mi < 2; ++mi) {
            const size_t off = kvbase + (mi * 16 + ln15) * 32 + lg * 8;
            f32x4 lo = {}, hi = {};
            #pragma unroll
            for (int sl = 0; sl < 4; ++sl) {
                const float* ap = KVf + (size_t)sl * 65536 + off;
                lo += *(const f32x4*)ap;
                hi += *(const f32x4*)(ap + 4);
            }
            a[mi] = bf16x8{(bf16)lo[0], (bf16)lo[1], (bf16)lo[2], (bf16)lo[3],
                           (bf16)hi[0], (bf16)hi[1], (bf16)hi[2], (bf16)hi[3]};
        }
        #pragma unroll
        for (int nj = 0; nj < 2; ++nj)
            b[nj] = *(const bf16x8*)&Qs[nj * 16 + ln15][h * 32 + lg * 8];
        f32x4 c[2][2];
        #pragma unroll
        for (int mi = 0; mi < 2; ++mi)
            #pragma unroll
            for (int nj = 0; nj < 2; ++nj) {
                f32x4 zz = {};
                c[mi][nj] = __builtin_amdgcn_mfma_f32_16x16x32_bf16(a[mi], b[nj], zz, 0, 0, 0);
            }
        #pragma unroll
        for (int nj = 0; nj < 2; ++nj) {
            const int l = nj * 16 + ln15;
            const float rcp = 1.f / (Dens[l][h] + EPSF);
            #pragma unroll
            for (int mi = 0; mi < 2; ++mi) {
                bf16x4 pk;
                #pragma unroll
                for (int r = 0; r < 4; ++r) pk[r] = (bf16)(c[mi][nj][r] * rcp);
                *(bf16x4*)&Qs[l][h * 32 + mi * 16 + lg * 4] = pk;
            }
        }
    }
    __syncthreads();

    {   // merge GEMM: out = Attn @ Wm^T (A from LDS, B from L2-hot Wm)
        f32x4 acc[2][4] = {};
        #pragma unroll 2
        for (int k0 = 0; k0 < 256; k0 += 32) {
            bf16x8 a[2], b[4];
            #pragma unroll
            for (int mi = 0; mi < 2; ++mi)
                a[mi] = *(const bf16x8*)&Qs[mi * 16 + ln15][k0 + lg * 8];
            #pragma unroll
            for (int ni = 0; ni < 4; ++ni)
                b[ni] = *(const bf16x8*)(Wm + (size_t)(wn + ni * 16 + ln15) * 256 + k0 + lg * 8);
            #pragma unroll
            for (int mi = 0; mi < 2; ++mi)
                #pragma unroll
                for (int ni = 0; ni < 4; ++ni)
                    acc[mi][ni] = __builtin_amdgcn_mfma_f32_16x16x32_bf16(
                        a[mi], b[ni], acc[mi][ni], 0, 0, 0);
        }
        #pragma unroll
        for (int ni = 0; ni < 4; ++ni) {
            const int col = wn + ni * 16 + ln15;
            #pragma unroll
            for (int mi = 0; mi < 2; ++mi)
                #pragma unroll
                for (int r = 0; r < 4; ++r)
                    out[(R0 + mi * 16 + lg * 4 + r) * 256 + col] = acc[mi][ni][r];
        }
    }
}

extern "C" void kernel_launch(void* const* d_in, const int* in_sizes, int n_in,
                              void* d_out, int out_size, void* d_ws, size_t ws_size,
                              hipStream_t stream) {
    const float* q      = (const float*)d_in[0];
    const float* k      = (const float*)d_in[1];
    const float* v      = (const float*)d_in[2];
    const int*   q_mask = (const int*)  d_in[3];
    const int*   kv_mask= (const int*)  d_in[4];
    const float* Wq     = (const float*)d_in[5];
    const float* bq     = (const float*)d_in[6];
    const float* Wk     = (const float*)d_in[7];
    const float* bk     = (const float*)d_in[8];
    const float* Wv     = (const float*)d_in[9];
    const float* bv     = (const float*)d_in[10];
    const float* Wm     = (const float*)d_in[11];

    char* ws = (char*)d_ws;
    bf16*  Wb   = (bf16*)ws;                        // 524288 B
    float* KVf  = (float*)(ws + 524288);            // 4 slices x 262144 B
    float* Ksum = (float*)(ws + 524288 + 1048576);  // 4 slices x 8192 B

    hipMemsetAsync(ws + 524288, 0, 1048576 + 32768, stream);

    const dim3 blk(256);
    wconv <<<dim3(256),    blk, 0, stream>>>(Wq, Wk, Wv, Wm, Wb);
    kvproj<<<dim3(2, 512), blk, 0, stream>>>(k, v, Wb, bk, bv, kv_mask, KVf, Ksum);
    attn  <<<dim3(128, 8), blk, 0, stream>>>(q, Wb, bq, q_mask, KVf, Ksum, (float*)d_out);
}

// Round 3
// 199.164 us; speedup vs baseline: 1.2921x; 1.2921x over previous
//
#include <hip/hip_runtime.h>

#define EPSF 1e-6f

typedef __bf16 bf16;
typedef bf16 bf16x4 __attribute__((ext_vector_type(4)));
typedef bf16 bf16x8 __attribute__((ext_vector_type(8)));
typedef float f32x4 __attribute__((ext_vector_type(4)));
typedef unsigned int u32;

// N=8, L=S=4096, E=256, H=8, D=32.
// MFMA 16x16x32 bf16 frags: A[m=lane&15][k=(lane>>4)*8+j], B[k][n=lane&15],
// C/D: col=lane&15, row=(lane>>4)*4+reg.
//
// R7: global f32 atomicAdd eliminated. Measured: device-scope atomics write
// through L2 to HBM (16B per 4B atomic; WRITE_SIZE == 16B x atomics) at a
// chip-wide ~40G atomics/s — kvproj's entire 99 us was atomic drain.
// kvproj now writes per-block KV/Ksum partials ONCE with coalesced stores
// (17.3 MB total) and a tiny kv_reduce kernel (R4-proven) sums them into
// bf16 KVb + f32 Ksum. attn reverted to the R4 l-tile-64 version (bf16 KVb
// frags direct). No KfT/VmT round-trip (kept from R5), no atomics, no memset.

__device__ __forceinline__ void async_ld16(const void* g, void* l) {
    __builtin_amdgcn_global_load_lds(
        (const __attribute__((address_space(1))) u32*)g,
        (__attribute__((address_space(3))) u32*)l, 16, 0, 0);
}

__global__ __launch_bounds__(256) void wconv(
    const float* __restrict__ Wq, const float* __restrict__ Wk,
    const float* __restrict__ Wv, const float* __restrict__ Wm,
    bf16* __restrict__ Wb)
{
    const int b = blockIdx.x, t = threadIdx.x;
    const int m = b >> 6;
    const float* S = (m == 0) ? Wq : (m == 1) ? Wk : (m == 2) ? Wv : Wm;
    const int idx = (b & 63) * 1024 + t * 4;
    float4 v = *(const float4*)(S + idx);
    bf16x4 p = {(bf16)v.x, (bf16)v.y, (bf16)v.z, (bf16)v.w};
    *(bf16x4*)(Wb + (size_t)m * 65536 + idx) = p;
}

// ---------------------------------------------------------------------------
// kvproj (fused): per (coltile, n, s-tile64) block computes K-proj AND V-proj
// tiles (z-loop, staging reused), then per-block partial KV (in-LDS MFMA)
// and Ksum partials, written ONCE with normal stores. grid (2, 512).
// Wave layout: each wave = all 64 rows x 32 cols (= one head).
// LDS: Kf [128 col][72 s] @0 (18432); staging Xs(8192)+Ws(8192) @18432;
//      Vm [128][72] @18432 aliases staging. Total 36864 -> 4 blocks/CU.
// part   layout: [n][st=64][h=8][v=32][d=32] f32 (16.78 MB)
// part_ks layout: [n][st=64][256] f32 (512 KB)
// ---------------------------------------------------------------------------
__global__ __launch_bounds__(256) void kvproj(
    const float* __restrict__ kin, const float* __restrict__ vin,
    const bf16* __restrict__ Wb,
    const float* __restrict__ bk, const float* __restrict__ bv,
    const int* __restrict__ kv_mask,
    float* __restrict__ part, float* __restrict__ part_ks)
{
    const int bx = blockIdx.x;                 // coltile (4 heads each)
    const int j0 = bx * 128;
    const int n  = blockIdx.y >> 6;
    const int st = blockIdx.y & 63;
    const int s0 = st * 64;
    const size_t R0 = (size_t)n * 4096 + s0;

    const int t = threadIdx.x, lane = t & 63, w = t >> 6;
    const int ln15 = lane & 15, lg = lane >> 4;
    const int wn = w * 32;                     // wave's col base (one head)
    const int wbase = t & ~63;

    __shared__ __align__(16) char smem[36864];
    bf16*  Kf_ld = (bf16*)smem;                      // [128 col][72 s]
    float* Xs    = (float*)(smem + 18432);           // 8192 B staging
    bf16*  Ws    = (bf16*)(smem + 18432 + 8192);     // 8192 B staging
    bf16*  Vm_ld = (bf16*)(smem + 18432);            // [128][72], aliases staging

    // kv-mask for this tile's 64 rows (same for K and V phases)
    float mv[4][4];
    #pragma unroll
    for (int mi = 0; mi < 4; ++mi)
        #pragma unroll
        for (int r = 0; r < 4; ++r)
            mv[mi][r] = kv_mask[R0 + mi * 16 + lg * 4 + r] ? 1.f : 0.f;

    #pragma unroll
    for (int z = 0; z < 2; ++z) {
        const float* X    = z ? vin : kin;
        const bf16*  W    = Wb + (size_t)(z + 1) * 65536;   // Wk, Wv
        const float* bias = z ? bv : bk;
        bf16* Yt          = z ? Vm_ld : Kf_ld;

        f32x4 acc[4][2] = {};

        for (int k0 = 0; k0 < 256; k0 += 32) {
            #pragma unroll
            for (int i = 0; i < 2; ++i) {     // X: 512 16B-slots (64 rows x 32 f32)
                const int c = i * 256 + t, row = c >> 3, sc = c & 7;
                async_ld16(X + (R0 + row) * 256 + k0 + ((sc ^ (row & 7)) * 4),
                           Xs + (size_t)(i * 256 + wbase) * 4);
            }
            #pragma unroll
            for (int i = 0; i < 2; ++i) {     // W: 512 slots, swizzle over row-pairs
                const int c = i * 256 + t, g = c >> 3, c8 = c & 7;
                const int c8s = c8 ^ (g & 7);
                const int wrow = g * 2 + (c8s >> 2), gch = c8s & 3;
                async_ld16(W + (size_t)(j0 + wrow) * 256 + k0 + gch * 8,
                           Ws + (size_t)(i * 256 + wbase) * 8);
            }
            __syncthreads();

            bf16x8 a[4], b[2];
            #pragma unroll
            for (int mi = 0; mi < 4; ++mi) {
                const int r = mi * 16 + ln15, rb = r & 7;
                f32x4 x0 = *(const f32x4*)&Xs[r * 32 + (((lg * 2)     ^ rb) * 4)];
                f32x4 x1 = *(const f32x4*)&Xs[r * 32 + (((lg * 2 + 1) ^ rb) * 4)];
                a[mi] = bf16x8{(bf16)x0[0], (bf16)x0[1], (bf16)x0[2], (bf16)x0[3],
                               (bf16)x1[0], (bf16)x1[1], (bf16)x1[2], (bf16)x1[3]};
            }
            #pragma unroll
            for (int ni = 0; ni < 2; ++ni) {
                const int wr = wn + ni * 16 + ln15, g = wr >> 1;
                const int c8 = ((wr & 1) * 4 + lg) ^ (g & 7);
                b[ni] = *(const bf16x8*)&Ws[g * 64 + c8 * 8];
            }
            #pragma unroll
            for (int mi = 0; mi < 4; ++mi)
                #pragma unroll
                for (int ni = 0; ni < 2; ++ni)
                    acc[mi][ni] = __builtin_amdgcn_mfma_f32_16x16x32_bf16(
                        a[mi], b[ni], acc[mi][ni], 0, 0, 0);
            __syncthreads();
        }

        // epilogue: bias (+elu+1 for K), mask, transpose to [col][s] in LDS.
        // (No /s on Vm: reference's /s and *s cancel.)
        float bb[2];
        #pragma unroll
        for (int ni = 0; ni < 2; ++ni) bb[ni] = bias[j0 + wn + ni * 16 + ln15];
        #pragma unroll
        for (int ni = 0; ni < 2; ++ni) {
            const int col = wn + ni * 16 + ln15;
            #pragma unroll
            for (int mi = 0; mi < 4; ++mi) {
                const int rowb = mi * 16 + lg * 4;
                bf16x4 pk;
                #pragma unroll
                for (int r = 0; r < 4; ++r) {
                    float x = acc[mi][ni][r] + bb[ni];
                    if (z == 0) x = (x > 0.f) ? (x + 1.f) : __expf(x);
                    pk[r] = (bf16)(x * mv[mi][r]);
                }
                *(bf16x4*)&Yt[col * 72 + rowb] = pk;
            }
        }
        __syncthreads();
    }

    // ---- Ksum partial: col-sums over this tile's 64 s-rows (stored once) ----
    {
        const int c = t >> 1, sh = t & 1;      // c in [0,128)
        const bf16* kp = Kf_ld + c * 72 + sh * 32;
        float s = 0.f;
        #pragma unroll
        for (int j = 0; j < 4; ++j) {
            bf16x8 vv = *(const bf16x8*)(kp + j * 8);
            #pragma unroll
            for (int jj = 0; jj < 8; ++jj) s += (float)vv[jj];
        }
        s += __shfl_xor(s, 1);
        if (sh == 0) part_ks[((size_t)(n * 64 + st)) * 256 + j0 + c] = s;
    }

    // ---- partial KV: wave w -> head bx*4+w, 32x32 over k-dim s=64 ----
    {
        const int cb = wn;                     // head-local col base in tile
        f32x4 c2[2][2] = {};
        #pragma unroll
        for (int step = 0; step < 2; ++step) {
            const int sb = step * 32 + lg * 8;
            bf16x8 a[2], b[2];
            #pragma unroll
            for (int mi = 0; mi < 2; ++mi)
                a[mi] = *(const bf16x8*)&Kf_ld[(cb + mi * 16 + ln15) * 72 + sb];
            #pragma unroll
            for (int nj = 0; nj < 2; ++nj)
                b[nj] = *(const bf16x8*)&Vm_ld[(cb + nj * 16 + ln15) * 72 + sb];
            #pragma unroll
            for (int mi = 0; mi < 2; ++mi)
                #pragma unroll
                for (int nj = 0; nj < 2; ++nj)
                    c2[mi][nj] = __builtin_amdgcn_mfma_f32_16x16x32_bf16(
                        a[mi], b[nj], c2[mi][nj], 0, 0, 0);
        }
        // D: col(v)=ln15, row(d)=lg*4+r -> store [v][d] (v-major), once.
        float* kvh = part + ((size_t)((n * 64 + st) * 8) + bx * 4 + w) * 1024;
        #pragma unroll
        for (int mi = 0; mi < 2; ++mi)
            #pragma unroll
            for (int nj = 0; nj < 2; ++nj)
                *(f32x4*)&kvh[(nj * 16 + ln15) * 32 + mi * 16 + lg * 4] = c2[mi][nj];
    }
}

// ---------------------------------------------------------------------------
// kv_reduce: sum 64 s-tile partials per (n,h) -> bf16 KVb + f32 Ksum.
// grid (64), 256 threads. ~17.3 MB read, coalesced.
// ---------------------------------------------------------------------------
__global__ __launch_bounds__(256) void kv_reduce(
    const float* __restrict__ part, const float* __restrict__ part_ks,
    bf16* __restrict__ KVb, float* __restrict__ Ksum)
{
    const int nh = blockIdx.x, n = nh >> 3, h = nh & 7;
    const int t = threadIdx.x;
    f32x4 acc = {};
    const float* p = part + ((size_t)n * 512 + h) * 1024 + t * 4;
    for (int c = 0; c < 64; ++c)
        acc += *(const f32x4*)(p + (size_t)c * 8192);
    bf16x4 ob = {(bf16)acc[0], (bf16)acc[1], (bf16)acc[2], (bf16)acc[3]};
    *(bf16x4*)(KVb + (size_t)nh * 1024 + t * 4) = ob;
    if (t < 32) {
        float s = 0.f;
        const float* pk = part_ks + (size_t)n * 16384 + h * 32 + t;
        for (int c = 0; c < 64; ++c) s += pk[c * 256];
        Ksum[n * 256 + h * 32 + t] = s;
    }
}

// ---------------------------------------------------------------------------
// attn: fused Q-proj (staged core) + linear attention + merge GEMM.
// grid (64, 8), 64-row l-tile, 256 threads. bf16 KVb frags direct.
// ---------------------------------------------------------------------------
__global__ __launch_bounds__(256) void attn(
    const float* __restrict__ qin, const bf16* __restrict__ Wb,
    const float* __restrict__ bq, const int* __restrict__ q_mask,
    const bf16* __restrict__ KVb, const float* __restrict__ Ksum,
    float* __restrict__ out)
{
    const int n = blockIdx.y, l0 = blockIdx.x * 64;
    const size_t R0 = (size_t)n * 4096 + l0;
    const int t = threadIdx.x, lane = t & 63, w = t >> 6;
    const int ln15 = lane & 15, lg = lane >> 4;
    const int wn = w * 64;
    const int wbase = t & ~63;

    const bf16* Wq = Wb;
    const bf16* Wm = Wb + 3 * 65536;

    __shared__ __align__(16) char smem[33792];
    float* Xs  = (float*)smem;           //  8192 B: q tile 64x32 f32 swizzled
    bf16*  Wst = (bf16*)(smem + 8192);   // 16384 B: Wq tile 256x32 swizzled
    bf16 (*Qs)[264] = (bf16(*)[264])smem;
    __shared__ float KSs[256];
    __shared__ float Dens[64][9];

    KSs[t] = Ksum[n * 256 + t];

    {   // ---- Q-projection, staged ----
        f32x4 acc[4][4] = {};
        for (int k0 = 0; k0 < 256; k0 += 32) {
            #pragma unroll
            for (int i = 0; i < 2; ++i) {     // X: 512 slots
                const int c = i * 256 + t, row = c >> 3, sc = c & 7;
                async_ld16(qin + (R0 + row) * 256 + k0 + ((sc ^ (row & 7)) * 4),
                           Xs + (size_t)(i * 256 + wbase) * 4);
            }
            #pragma unroll
            for (int i = 0; i < 4; ++i) {     // W: 1024 slots (all 256 rows)
                const int c = i * 256 + t, g = c >> 3, c8 = c & 7;
                const int c8s = c8 ^ (g & 7);
                const int wrow = g * 2 + (c8s >> 2), gch = c8s & 3;
                async_ld16(Wq + (size_t)wrow * 256 + k0 + gch * 8,
                           Wst + (size_t)(i * 256 + wbase) * 8);
            }
            __syncthreads();

            bf16x8 a[4], b[4];
            #pragma unroll
            for (int mi = 0; mi < 4; ++mi) {
                const int r = mi * 16 + ln15, rb = r & 7;
                f32x4 x0 = *(const f32x4*)&Xs[r * 32 + (((lg * 2)     ^ rb) * 4)];
                f32x4 x1 = *(const f32x4*)&Xs[r * 32 + (((lg * 2 + 1) ^ rb) * 4)];
                a[mi] = bf16x8{(bf16)x0[0], (bf16)x0[1], (bf16)x0[2], (bf16)x0[3],
                               (bf16)x1[0], (bf16)x1[1], (bf16)x1[2], (bf16)x1[3]};
            }
            #pragma unroll
            for (int ni = 0; ni < 4; ++ni) {
                const int wr = wn + ni * 16 + ln15, g = wr >> 1;
                const int c8 = ((wr & 1) * 4 + lg) ^ (g & 7);
                b[ni] = *(const bf16x8*)&Wst[g * 64 + c8 * 8];
            }
            #pragma unroll
            for (int mi = 0; mi < 4; ++mi)
                #pragma unroll
                for (int ni = 0; ni < 4; ++ni)
                    acc[mi][ni] = __builtin_amdgcn_mfma_f32_16x16x32_bf16(
                        a[mi], b[ni], acc[mi][ni], 0, 0, 0);
            __syncthreads();
        }
        float bb[4];
        #pragma unroll
        for (int ni = 0; ni < 4; ++ni) bb[ni] = bq[wn + ni * 16 + ln15];
        float mv[4][4];
        #pragma unroll
        for (int mi = 0; mi < 4; ++mi)
            #pragma unroll
            for (int r = 0; r < 4; ++r)
                mv[mi][r] = q_mask[R0 + mi * 16 + lg * 4 + r] ? 1.f : 0.f;
        #pragma unroll
        for (int mi = 0; mi < 4; ++mi)
            #pragma unroll
            for (int r = 0; r < 4; ++r) {
                const int row = mi * 16 + lg * 4 + r;
                #pragma unroll
                for (int ni = 0; ni < 4; ++ni) {
                    float x = acc[mi][ni][r] + bb[ni];
                    x = (x > 0.f) ? (x + 1.f) : __expf(x);
                    Qs[row][wn + ni * 16 + ln15] = (bf16)(x * mv[mi][r]);
                }
            }
    }
    __syncthreads();

    #pragma unroll
    for (int i = 0; i < 2; ++i) {   // den[l][h]
        const int idx = t + i * 256;
        const int l = idx & 63, h = idx >> 6;
        float s = 0.f;
        #pragma unroll
        for (int d8 = 0; d8 < 4; ++d8) {
            bf16x8 qv = *(const bf16x8*)&Qs[l][h * 32 + d8 * 8];
            #pragma unroll
            for (int jj = 0; jj < 8; ++jj)
                s += (float)qv[jj] * KSs[h * 32 + d8 * 8 + jj];
        }
        Dens[l][h] = s;
    }
    __syncthreads();

    #pragma unroll
    for (int hh = 0; hh < 2; ++hh) {   // num + normalize (wave-disjoint cols)
        const int h = w * 2 + hh;
        const bf16* kvh = KVb + (size_t)(n * 8 + h) * 1024;
        bf16x8 a[2], b[4];
        #pragma unroll
        for (int mi = 0; mi < 2; ++mi)
            a[mi] = *(const bf16x8*)(kvh + (mi * 16 + ln15) * 32 + lg * 8);
        #pragma unroll
        for (int nj = 0; nj < 4; ++nj)
            b[nj] = *(const bf16x8*)&Qs[nj * 16 + ln15][h * 32 + lg * 8];
        f32x4 c[2][4];
        #pragma unroll
        for (int mi = 0; mi < 2; ++mi)
            #pragma unroll
            for (int nj = 0; nj < 4; ++nj) {
                f32x4 zz = {};
                c[mi][nj] = __builtin_amdgcn_mfma_f32_16x16x32_bf16(a[mi], b[nj], zz, 0, 0, 0);
            }
        #pragma unroll
        for (int nj = 0; nj < 4; ++nj) {
            const int l = nj * 16 + ln15;
            const float rcp = 1.f / (Dens[l][h] + EPSF);
            #pragma unroll
            for (int mi = 0; mi < 2; ++mi) {
                bf16x4 pk;
                #pragma unroll
                for (int r = 0; r < 4; ++r) pk[r] = (bf16)(c[mi][nj][r] * rcp);
                *(bf16x4*)&Qs[l][h * 32 + mi * 16 + lg * 4] = pk;
            }
        }
    }
    __syncthreads();

    {   // merge GEMM: out = Attn @ Wm^T (A from LDS, B from L2-hot Wm)
        f32x4 acc[4][4] = {};
        #pragma unroll 2
        for (int k0 = 0; k0 < 256; k0 += 32) {
            bf16x8 a[4], b[4];
            #pragma unroll
            for (int mi = 0; mi < 4; ++mi)
                a[mi] = *(const bf16x8*)&Qs[mi * 16 + ln15][k0 + lg * 8];
            #pragma unroll
            for (int ni = 0; ni < 4; ++ni)
                b[ni] = *(const bf16x8*)(Wm + (size_t)(wn + ni * 16 + ln15) * 256 + k0 + lg * 8);
            #pragma unroll
            for (int mi = 0; mi < 4; ++mi)
                #pragma unroll
                for (int ni = 0; ni < 4; ++ni)
                    acc[mi][ni] = __builtin_amdgcn_mfma_f32_16x16x32_bf16(
                        a[mi], b[ni], acc[mi][ni], 0, 0, 0);
        }
        #pragma unroll
        for (int ni = 0; ni < 4; ++ni) {
            const int col = wn + ni * 16 + ln15;
            #pragma unroll
            for (int mi = 0; mi < 4; ++mi)
                #pragma unroll
                for (int r = 0; r < 4; ++r)
                    out[(R0 + mi * 16 + lg * 4 + r) * 256 + col] = acc[mi][ni][r];
        }
    }
}

extern "C" void kernel_launch(void* const* d_in, const int* in_sizes, int n_in,
                              void* d_out, int out_size, void* d_ws, size_t ws_size,
                              hipStream_t stream) {
    const float* q      = (const float*)d_in[0];
    const float* k      = (const float*)d_in[1];
    const float* v      = (const float*)d_in[2];
    const int*   q_mask = (const int*)  d_in[3];
    const int*   kv_mask= (const int*)  d_in[4];
    const float* Wq     = (const float*)d_in[5];
    const float* bq     = (const float*)d_in[6];
    const float* Wk     = (const float*)d_in[7];
    const float* bk     = (const float*)d_in[8];
    const float* Wv     = (const float*)d_in[9];
    const float* bv     = (const float*)d_in[10];
    const float* Wm     = (const float*)d_in[11];

    char* ws = (char*)d_ws;
    bf16*  Wb      = (bf16*)ws;                                  // 524288 B
    float* part    = (float*)(ws + 524288);                      // 16777216 B
    float* part_ks = (float*)(ws + 524288 + 16777216);           // 524288 B
    bf16*  KVb     = (bf16*)(ws + 524288 + 16777216 + 524288);   // 131072 B
    float* Ksum    = (float*)(ws + 524288 + 16777216 + 524288 + 131072); // 8192 B

    const dim3 blk(256);
    wconv    <<<dim3(256),    blk, 0, stream>>>(Wq, Wk, Wv, Wm, Wb);
    kvproj   <<<dim3(2, 512), blk, 0, stream>>>(k, v, Wb, bk, bv, kv_mask, part, part_ks);
    kv_reduce<<<dim3(64),     blk, 0, stream>>>(part, part_ks, KVb, Ksum);
    attn     <<<dim3(64, 8),  blk, 0, stream>>>(q, Wb, bq, q_mask, KVb, Ksum, (float*)d_out);
}